// Round 4
// baseline (25.735 us; speedup 1.0000x reference)
//
#include <hip/hip_runtime.h>

#define BB 4
#define SS 8192
#define DD 1024
#define TPB 256
#define EPT 32            // boundary elements per thread = SS / TPB
#define ROWS 4            // output rows per block (one per wave)

typedef float vf4 __attribute__((ext_vector_type(4)));  // clang-native for nontemporal builtins

// Fully fused: each block recomputes the per-batch stable-partition scan
// (boundaries are tiny and L2-resident) and gathers its 4 output rows.
// No inter-kernel dependency, single dispatch.
__global__ __launch_bounds__(TPB) void chunk_fused(const void* __restrict__ bptr,
                                                   const float* __restrict__ x,
                                                   float* __restrict__ out,
                                                   float* __restrict__ ntok,
                                                   int max_chunks, int groups) {
    const int gb = blockIdx.x;
    const int b = gb / groups;
    const int g = gb % groups;
    const int row0 = g * ROWS;
    const int t = threadIdx.x;
    const int lane = t & 63;
    const int wave = t >> 6;

    // ---- dtype detection over the first 32 KB (valid window for all views) ----
    // f: 0 = int32, 1 = byte-bool, 2 = float32
    __shared__ int s_non, s_mis;
    if (t == 0) { s_non = 0; s_mis = 0; }
    __syncthreads();
    {
        const uint4* __restrict__ wp = (const uint4*)bptr;   // 2048 uint4 = 32 KB
        unsigned int accNon = 0, accMis = 0;
        #pragma unroll
        for (int r = 0; r < 8; ++r) {
            uint4 w = wp[t + r * TPB];
            accNon |= (w.x | w.y | w.z | w.w) & 0xFEFEFEFEu;  // any byte > 1
            accMis |= (w.x | w.y | w.z | w.w) & 0xFFFFFF00u;  // any misaligned byte != 0
        }
        if (accNon) atomicOr(&s_non, 1);
        if (accMis) atomicOr(&s_mis, 1);
    }
    __syncthreads();
    const int f = s_non ? 2 : (s_mis ? 1 : 0);

    // ---- load this batch's boundaries: 32 contiguous elements per thread → bitmask ----
    unsigned int mask = 0;
    if (f == 0) {
        const int4* __restrict__ p = (const int4*)((const int*)bptr + b * SS);
        #pragma unroll
        for (int r = 0; r < 8; ++r) {
            int4 w = p[t * 8 + r];
            mask |= (unsigned int)((w.x != 0) | ((w.y != 0) << 1) |
                                   ((w.z != 0) << 2) | ((w.w != 0) << 3)) << (r * 4);
        }
    } else if (f == 1) {
        const uint4* __restrict__ p = (const uint4*)((const unsigned char*)bptr + b * SS);
        uint4 w0 = p[t * 2], w1 = p[t * 2 + 1];
        unsigned int ws[8] = {w0.x, w0.y, w0.z, w0.w, w1.x, w1.y, w1.z, w1.w};
        #pragma unroll
        for (int q = 0; q < 8; ++q) {
            unsigned int v = ws[q];
            mask |= (unsigned int)(((v & 0xFFu) != 0u) |
                                   (((v >> 8) & 0xFFu) != 0u) << 1 |
                                   (((v >> 16) & 0xFFu) != 0u) << 2 |
                                   (((v >> 24) & 0xFFu) != 0u) << 3) << (q * 4);
        }
    } else {
        const float4* __restrict__ p = (const float4*)((const float*)bptr + b * SS);
        #pragma unroll
        for (int r = 0; r < 8; ++r) {
            float4 w = p[t * 8 + r];
            mask |= (unsigned int)((w.x != 0.0f) | ((w.y != 0.0f) << 1) |
                                   ((w.z != 0.0f) << 2) | ((w.w != 0.0f) << 3)) << (r * 4);
        }
    }
    const int cnt = __popc(mask);

    // ---- wave scan of per-thread counts + block combine ----
    int scan = cnt;
    #pragma unroll
    for (int o = 1; o < 64; o <<= 1) {
        int n = __shfl_up(scan, o, 64);
        if (lane >= o) scan += n;
    }
    __shared__ int waveTot[4];
    __shared__ int waveOff[4];
    __shared__ int s_total;
    __shared__ int s_rowj[ROWS];
    if (lane == 63) waveTot[wave] = scan;
    __syncthreads();
    if (t == 0) {
        int acc = 0;
        #pragma unroll
        for (int w = 0; w < 4; ++w) { waveOff[w] = acc; acc += waveTot[w]; }
        s_total = acc;
    }
    __syncthreads();
    const int T = s_total;

    // ---- compute dests; capture the source rows this block owns ----
    int tr = waveOff[wave] + (scan - cnt);   // exclusive prefix of trues
    #pragma unroll
    for (int k = 0; k < EPT; ++k) {
        const int j = t * EPT + k;
        int dest;
        if ((mask >> k) & 1u) { dest = tr; tr++; }
        else                  { dest = T + (j - tr); }
        const int rel = dest - row0;
        if ((unsigned)rel < (unsigned)ROWS) s_rowj[rel] = j;
    }
    if (g == 0 && t == 0) ntok[b] = (float)T;
    __syncthreads();

    // ---- gather: one wave per row, 4 x float4 per lane, non-temporal ----
    const int c = row0 + wave;
    if (c < max_chunks) {
        const int j = s_rowj[wave];
        const vf4* __restrict__ src =
            (const vf4*)(x + ((long long)b * SS + (long long)j) * DD);
        vf4* __restrict__ dst =
            (vf4*)(out + ((long long)b * max_chunks + c) * (long long)DD);
        #pragma unroll
        for (int r = 0; r < 4; ++r) {
            vf4 v = __builtin_nontemporal_load(&src[lane + 64 * r]);
            __builtin_nontemporal_store(v, &dst[lane + 64 * r]);
        }
    }
}

extern "C" void kernel_launch(void* const* d_in, const int* in_sizes, int n_in,
                              void* d_out, int out_size, void* d_ws, size_t ws_size,
                              hipStream_t stream) {
    const float* x = (const float*)d_in[0];
    const void* bptr = d_in[1];
    float* out = (float*)d_out;

    const int max_chunks = (out_size - BB) / (BB * DD);
    const int groups = (max_chunks + ROWS - 1) / ROWS;
    float* ntok = out + (long long)BB * max_chunks * DD;

    chunk_fused<<<BB * groups, TPB, 0, stream>>>(bptr, x, out, ntok, max_chunks, groups);
}

// Round 5
// 21.209 us; speedup vs baseline: 1.2134x; 1.2134x over previous
//
#include <hip/hip_runtime.h>

#define BB 4
#define SS 8192
#define DD 1024

typedef float vf4 __attribute__((ext_vector_type(4)));

// One block per batch, 1024 threads, 8 boundary elements/thread.
// (a) dtype detection of `boundaries` (int32 / byte-bool / float32) over a
//     16 KB window, (b) stable-partition prefix scan, (c) scatter of
//     sel[b][c] = source row index, (d) num_tokens write.
__global__ __launch_bounds__(1024) void build_sel(const void* __restrict__ bptr,
                                                  int* __restrict__ sel,
                                                  float* __restrict__ ntok_out,
                                                  int max_chunks) {
    const int b = blockIdx.x;
    const int t = threadIdx.x;

    // ---- dtype detection: 1024 threads x 1 uint4 = 16 KB window ----
    __shared__ int s_non, s_mis;
    if (t == 0) { s_non = 0; s_mis = 0; }
    __syncthreads();
    {
        const uint4* __restrict__ wp = (const uint4*)bptr;
        uint4 w = wp[t];
        unsigned int o = w.x | w.y | w.z | w.w;
        if (o & 0xFEFEFEFEu) atomicOr(&s_non, 1);   // any byte > 1  -> float32
        if (o & 0xFFFFFF00u) atomicOr(&s_mis, 1);   // misaligned byte != 0 -> byte bool
    }
    __syncthreads();
    const int f = s_non ? 2 : (s_mis ? 1 : 0);

    // ---- vectorized boundary read: 8 elements per thread ----
    const int base = t * 8;
    unsigned char vals[8];
    int cnt = 0;
    if (f == 0) {
        const int4* __restrict__ p = (const int4*)((const int*)bptr + b * SS);
        int4 w0 = p[t * 2], w1 = p[t * 2 + 1];
        int vi[8] = {w0.x, w0.y, w0.z, w0.w, w1.x, w1.y, w1.z, w1.w};
        #pragma unroll
        for (int k = 0; k < 8; ++k) { vals[k] = vi[k] != 0; cnt += vals[k]; }
    } else if (f == 1) {
        const uint2* __restrict__ p = (const uint2*)((const unsigned char*)bptr + b * SS);
        uint2 w = p[t];
        unsigned int ws[2] = {w.x, w.y};
        #pragma unroll
        for (int k = 0; k < 8; ++k) {
            vals[k] = ((ws[k >> 2] >> ((k & 3) * 8)) & 0xFFu) != 0u;
            cnt += vals[k];
        }
    } else {
        const float4* __restrict__ p = (const float4*)((const float*)bptr + b * SS);
        float4 w0 = p[t * 2], w1 = p[t * 2 + 1];
        float vf[8] = {w0.x, w0.y, w0.z, w0.w, w1.x, w1.y, w1.z, w1.w};
        #pragma unroll
        for (int k = 0; k < 8; ++k) { vals[k] = vf[k] != 0.0f; cnt += vals[k]; }
    }

    // ---- wave-level (64-lane) inclusive scan of per-thread counts ----
    const int lane = t & 63;
    const int wave = t >> 6;
    int scan = cnt;
    #pragma unroll
    for (int o = 1; o < 64; o <<= 1) {
        int n = __shfl_up(scan, o, 64);
        if (lane >= o) scan += n;
    }

    __shared__ int waveTot[16];
    __shared__ int waveOff[16];
    __shared__ int total;
    if (lane == 63) waveTot[wave] = scan;
    __syncthreads();
    if (t == 0) {
        int acc = 0;
        #pragma unroll
        for (int w = 0; w < 16; ++w) { waveOff[w] = acc; acc += waveTot[w]; }
        total = acc;
    }
    __syncthreads();

    const int T = total;
    int trueBefore = waveOff[wave] + (scan - cnt);   // exclusive prefix of trues
    int falseBefore = base - trueBefore;             // exclusive prefix of falses

    #pragma unroll
    for (int k = 0; k < 8; ++k) {
        const int j = base + k;
        int dest;
        if (vals[k]) dest = trueBefore++;
        else         dest = T + falseBefore++;
        if (dest < max_chunks) sel[b * max_chunks + dest] = j;
    }
    if (t == 0) ntok_out[b] = (float)T;
}

// Two rows per wave, 8 rows per 256-thread block: 8 float4 loads in flight,
// then 8 stores. Fully coalesced 4 KB rows on both sides.
__global__ __launch_bounds__(256) void gather_rows(const float* __restrict__ x,
                                                   const int* __restrict__ sel,
                                                   float* __restrict__ out,
                                                   int max_chunks, int nrows) {
    const int wave = threadIdx.x >> 6;
    const int lane = threadIdx.x & 63;
    const long long row0 = (long long)blockIdx.x * 8 + wave * 2;
    const long long row1 = row0 + 1;
    if (row0 >= nrows) return;
    const bool has1 = (row1 < nrows);

    const int b0 = (int)(row0 / max_chunks);
    const int j0 = sel[row0];
    const vf4* __restrict__ s0 = (const vf4*)(x + ((long long)b0 * SS + j0) * DD);
    vf4* __restrict__ d0 = (vf4*)(out + row0 * (long long)DD);

    const int b1 = has1 ? (int)(row1 / max_chunks) : b0;
    const int j1 = has1 ? sel[row1] : j0;
    const vf4* __restrict__ s1 = (const vf4*)(x + ((long long)b1 * SS + j1) * DD);
    vf4* __restrict__ d1 = (vf4*)(out + row1 * (long long)DD);

    vf4 a0 = s0[lane], a1 = s0[lane + 64], a2 = s0[lane + 128], a3 = s0[lane + 192];
    vf4 c0 = s1[lane], c1 = s1[lane + 64], c2 = s1[lane + 128], c3 = s1[lane + 192];

    d0[lane] = a0; d0[lane + 64] = a1; d0[lane + 128] = a2; d0[lane + 192] = a3;
    if (has1) {
        d1[lane] = c0; d1[lane + 64] = c1; d1[lane + 128] = c2; d1[lane + 192] = c3;
    }
}

extern "C" void kernel_launch(void* const* d_in, const int* in_sizes, int n_in,
                              void* d_out, int out_size, void* d_ws, size_t ws_size,
                              hipStream_t stream) {
    const float* x = (const float*)d_in[0];
    const void* bptr = d_in[1];
    float* out = (float*)d_out;

    const int max_chunks = (out_size - BB) / (BB * DD);
    const int nrows = BB * max_chunks;

    int* sel = (int*)d_ws;
    float* ntok = out + (long long)nrows * DD;

    build_sel<<<BB, 1024, 0, stream>>>(bptr, sel, ntok, max_chunks);
    gather_rows<<<(nrows + 7) / 8, 256, 0, stream>>>(x, sel, out, max_chunks, nrows);
}